// Round 6
// baseline (642.020 us; speedup 1.0000x reference)
//
#include <hip/hip_runtime.h>
#include <hip/hip_bf16.h>

#define SQ2 0.70710678118654752440f

typedef __attribute__((ext_vector_type(4))) float f32x4;
typedef __attribute__((ext_vector_type(16))) float f32x16;
typedef __attribute__((ext_vector_type(8))) short s16x8;

// B=16, Cin=256, H=W=64.  rimg channels = 512 (0..255 = branch0, 256..511 = x identity)

__device__ __forceinline__ unsigned short f2bf(float f){
  unsigned u = __builtin_bit_cast(unsigned, f);
  u += 0x7FFFu + ((u >> 16) & 1u);
  return (unsigned short)(u >> 16);
}

__device__ __forceinline__ void gload16(const void* g, const void* l){
  __builtin_amdgcn_global_load_lds((const __attribute__((address_space(1))) void*)g,
                                   (__attribute__((address_space(3))) void*)l, 16, 0, 0);
}

// ---------------- weight converts ----------------
__global__ void k_cvt_cw(const float* __restrict__ w, unsigned short* __restrict__ o){
  int g = blockIdx.x * blockDim.x + threadIdx.x;
  if (g < 256*256) o[g] = f2bf(w[g]);
}

// convW_w [o=256][cin=512][kh=3][kw=3] f32  ->  Wb [tap=kh*3+kw][o][cin] bf16
__global__ void k_cvt_wb(const float* __restrict__ w, unsigned short* __restrict__ o){
  const int N = 256*512*9;
  for (int g = blockIdx.x*blockDim.x + threadIdx.x; g < N; g += gridDim.x*blockDim.x){
    int tap = g % 9;
    int t2  = g / 9;
    int cin = t2 & 511;
    int oc  = t2 >> 9;
    o[(tap*256 + oc)*512 + cin] = f2bf(w[g]);
  }
}

// ---------------- x (NCHW f32) -> Cb NHWC bf16, channels 256..511 ----------------
__global__ __launch_bounds__(256) void k_x_nhwc(const float* __restrict__ x,
                                                unsigned short* __restrict__ Cb){
  __shared__ float tile[32][65];
  int bh = blockIdx.x;            // b*64 + h
  int b = bh >> 6, h = bh & 63;
  int t = threadIdx.x;
  for (int cc = 0; cc < 256; cc += 32){
    int w = t & 63, c4 = t >> 6;
#pragma unroll
    for (int r = 0; r < 8; ++r){
      int c = c4*8 + r;
      tile[c][w] = x[((b*256 + cc + c)*64 + h)*64 + w];
    }
    __syncthreads();
    int c = t & 31, w4 = t >> 5;
#pragma unroll
    for (int r = 0; r < 8; ++r){
      int w2 = w4*8 + r;
      Cb[((b*64 + h)*64 + w2)*512 + 256 + cc + c] = f2bf(tile[c][w2]);
    }
    __syncthreads();
  }
}

// ---------------- fused 1x1 conv (bf16 MFMA) + Haar DWT -> subbands f32 ----------------
// subbands layout: [s=0(A),1(H),2(V),3(D)][b=16][i=32][j=32][o=256] f32 (lives in d_out)
__global__ __launch_bounds__(256) void k_gemm1_dwt(const unsigned short* __restrict__ Cb,
                                                   const unsigned short* __restrict__ cw,
                                                   float* __restrict__ sub){
  int d = blockIdx.x;                      // 2048 = 16b * 32rowpair * 4otile (XCD-swizzled)
  int xcd = d & 7, idx = d >> 3;           // idx 0..255
  int b = xcd*2 + (idx >> 7);
  int rest = idx & 127;
  int rp = rest >> 2, ot = rest & 3;
  int tid = threadIdx.x, wave = tid >> 6, l = tid & 63;
  int l16 = l & 15, lg = l >> 4;
  int obase = ot * 64;
  f32x4 acc[2][4];
#pragma unroll
  for (int i = 0; i < 2; ++i)
#pragma unroll
    for (int j = 0; j < 4; ++j) acc[i][j] = (f32x4)0.0f;

  // pixel p = wave*32 + mt*16 + (lane part);  p = 2*w + rr  (rr = row within pair)
  for (int cc = 0; cc < 256; cc += 32){
    s16x8 a[2], bf[4];
#pragma unroll
    for (int mt = 0; mt < 2; ++mt){
      int p  = wave*32 + mt*16 + l16;
      int w  = p >> 1, rr = p & 1;
      int hin = rp*2 + rr;
      a[mt] = *(const s16x8*)(Cb + ((b*64 + hin)*64 + w)*512 + 256 + cc + lg*8);
    }
#pragma unroll
    for (int nt = 0; nt < 4; ++nt){
      int o = obase + nt*16 + l16;
      bf[nt] = *(const s16x8*)(cw + o*256 + cc + lg*8);
    }
#pragma unroll
    for (int mt = 0; mt < 2; ++mt)
#pragma unroll
      for (int nt = 0; nt < 4; ++nt)
        acc[mt][nt] = __builtin_amdgcn_mfma_f32_16x16x32_bf16(a[mt], bf[nt], acc[mt][nt], 0, 0, 0);
  }

#pragma unroll
  for (int mt = 0; mt < 2; ++mt){
    int j = wave*8 + mt*4 + lg;            // column index in subband
#pragma unroll
    for (int nt = 0; nt < 4; ++nt){
      int o = obase + nt*16 + l16;
      f32x4 v = acc[mt][nt];
      float lo0 = (v.x + v.y)*SQ2, hi0 = (v.x - v.y)*SQ2;
      float lo1 = (v.z + v.w)*SQ2, hi1 = (v.z - v.w)*SQ2;
      float cA = (lo0 + lo1)*SQ2, cV = (lo0 - lo1)*SQ2;
      float cH = (hi0 + hi1)*SQ2, cD = (hi0 - hi1)*SQ2;
      int base = ((b*32 + rp)*32 + j)*256 + o;
      sub[base]              = cA;
      sub[base +   4194304]  = cH;
      sub[base + 2*4194304]  = cV;
      sub[base + 3*4194304]  = cD;
    }
  }
}

// ---------------- per-subband per-channel batch stats ----------------
__global__ __launch_bounds__(256) void k_stats_sub(const float* __restrict__ sub,
                                                   float* __restrict__ statsA){
  int bx = blockIdx.x;                 // 512 = 4s * 16b * 8posgroup
  int pg = bx & 7, b = (bx >> 3) & 15, s = bx >> 7;
  int t = threadIdx.x;
  const float* base = sub + (size_t)(s*16 + b)*262144 + pg*128*256;
  float sum = 0.f, sq = 0.f;
  for (int pos = 0; pos < 128; ++pos){
    float v = base[pos*256 + t];
    sum += v; sq += v*v;
  }
  atomicAdd(&statsA[(s*256 + t)*2],     sum);
  atomicAdd(&statsA[(s*256 + t)*2 + 1], sq);
}

__global__ void k_fin_A(const float* __restrict__ statsA, const float* __restrict__ gamma,
                        const float* __restrict__ beta, float* __restrict__ bnA){
  int t = blockIdx.x*blockDim.x + threadIdx.x;   // 1024 = 4s*256c
  if (t >= 1024) return;
  int c = t & 255;
  const float n = 16384.f;
  float mean = statsA[t*2] / n;
  float var  = statsA[t*2+1] / n - mean*mean;
  float sc = gamma[c] * rsqrtf(var + 1e-5f);
  bnA[t*2]   = sc;
  bnA[t*2+1] = beta[c] - mean*sc;
}

// ---------------- BN + ReLU + IDWT -> Cb NHWC bf16 channels 0..255 ----------------
__global__ __launch_bounds__(256) void k_bn_idwt(const float* __restrict__ sub,
                                                 const float* __restrict__ bnA,
                                                 unsigned short* __restrict__ Cb){
  int bx = blockIdx.x;                 // 512 = 16b * 32i
  int b = bx >> 5, i = bx & 31;
  int c = threadIdx.x;
  float scA = bnA[c*2],              shA = bnA[c*2+1];
  float scH = bnA[(256+c)*2],        shH = bnA[(256+c)*2+1];
  float scV = bnA[(512+c)*2],        shV = bnA[(512+c)*2+1];
  float scD = bnA[(768+c)*2],        shD = bnA[(768+c)*2+1];
  for (int j = 0; j < 32; ++j){
    size_t idx = ((size_t)(b*32 + i)*32 + j)*256 + c;
    float a  = fmaxf(sub[idx]              * scA + shA, 0.f);
    float hh = fmaxf(sub[idx +   4194304]  * scH + shH, 0.f);
    float v  = fmaxf(sub[idx + 2*4194304]  * scV + shV, 0.f);
    float d  = fmaxf(sub[idx + 3*4194304]  * scD + shD, 0.f);
    float lo_e = (a + v)*SQ2, lo_o = (a - v)*SQ2;
    float hi_e = (hh + d)*SQ2, hi_o = (hh - d)*SQ2;
    int h2 = 2*i, w2 = 2*j;
    Cb[((b*64 + h2  )*64 + w2  )*512 + c] = f2bf((lo_e + hi_e)*SQ2);
    Cb[((b*64 + h2  )*64 + w2+1)*512 + c] = f2bf((lo_o + hi_o)*SQ2);
    Cb[((b*64 + h2+1)*64 + w2  )*512 + c] = f2bf((lo_e - hi_e)*SQ2);
    Cb[((b*64 + h2+1)*64 + w2+1)*512 + c] = f2bf((lo_o - hi_o)*SQ2);
  }
}

// ---------------- 3x3 conv, 512->256, implicit GEMM, 32x32x16 MFMA ----------------
// Block: 64o x (4r x 64c), 512 thr (8 waves: wo=wv&1 -> 32o, wp=wv>>1 -> row).
// Wave: 32o x 64px, acc = 2 x f32x16 (32 AGPR) -> 4 waves/SIMD, 2 blocks/CU.
// Grid 1024 = 16b x 16rg x 4og, XCD-swizzled. 288 phases (32 chunk x 9 tap), 1 barrier each.
// LDS: ibuf 2x16KB [2pl x 6r x 66c x 16B slots, pad 1024]; wbuf 2x2KB [2pl x 64o]. 36864 B.
// Fused: final-BN stats (sum, sumsq per o) via shfl butterfly + atomicAdd.
__global__ __launch_bounds__(512, 4) void k_conv3(const unsigned short* __restrict__ Cb,
                                                  const unsigned short* __restrict__ Wb,
                                                  const unsigned short* __restrict__ guard,
                                                  const float* __restrict__ bias,
                                                  float* __restrict__ y,
                                                  float* __restrict__ statsY){
  __shared__ char sm[36864];

  int d = blockIdx.x;                  // 1024 blocks
  int xcd = d & 7, idx = d >> 3;       // idx 0..127
  int b   = xcd*2 + (idx >> 6);
  int rem = idx & 63;
  int rg = rem >> 2, og = rem & 3;
  int h0 = rg*4, obase = og*64;

  int tid = threadIdx.x, wv = tid >> 6, l = tid & 63;
  int l32 = l & 31, lh = l >> 5;
  int wo = wv & 1, wp = wv >> 1;

  // ---- input staging: 792 slots (2pl x 6r x 66c), 2 rounds of 512 ----
  const unsigned short* ip[2]; int iadv[2];
#pragma unroll
  for (int k = 0; k < 2; ++k){
    int j = tid + 512*k;
    const unsigned short* p = guard; int adv = 0;
    if (j < 792){
      int pl = j/396, q = j%396, rr = q/66, c = q%66;
      int hin = h0 - 1 + rr, win = c - 1;
      if ((unsigned)hin < 64u && (unsigned)win < 64u){
        p = Cb + (((b*64 + hin)*64 + win)*512 + pl*8);
        adv = 16;
      }
    }
    ip[k] = p; iadv[k] = adv;
  }

  // ---- weight staging: 128 slots (2pl x 64o), waves 0-1 ----
  int ws  = wv*64 + l;                 // 0..127 when wv<2
  int wpl = ws >> 6, wob = ws & 63;
  const unsigned short* wg = Wb + ((obase + wob)*512 + wpl*8);  // + tap*131072 + sc*16

  f32x16 acc0 = (f32x16)0.0f, acc1 = (f32x16)0.0f;

  // ---- prologue: I(chunk0) -> ibuf0, W(0,0) -> wbuf0 ----
  gload16(ip[0], sm + tid*16);
  gload16(ip[1], sm + 8192 + tid*16);
  if (wv < 2) gload16(wg, sm + 32768 + ws*16);

  int pp = 0;                          // weight buffer parity of CURRENT phase
  for (int sc = 0; sc < 32; ++sc){
    char* ibc = sm + (sc & 1)*16384;
    char* ibn = sm + ((sc & 1) ^ 1)*16384;
#pragma unroll
    for (int tau = 0; tau < 9; ++tau){
      asm volatile("s_waitcnt vmcnt(0)" ::: "memory");
      __builtin_amdgcn_s_barrier();
      char* wbc = sm + 32768 + pp*2048;
      char* wbn = sm + 32768 + (pp ^ 1)*2048;
      int p = sc*9 + tau;
      if (p < 287){
        int ntap = (tau < 8) ? tau + 1 : 0;
        int nsc  = (tau < 8) ? sc : sc + 1;
        if (wv < 2) gload16(wg + ntap*131072 + nsc*16, wbn + ws*16);
        if (tau == 8){
          ip[0] += iadv[0]; ip[1] += iadv[1];
          gload16(ip[0], ibn + tid*16);
          gload16(ip[1], ibn + 8192 + tid*16);
        }
      }
      const int kh = tau / 3, kw = tau % 3;
      s16x8 A  = *(const s16x8*)(wbc + ((lh*64 + wo*32 + l32) << 4));
      s16x8 B0 = *(const s16x8*)(ibc + ((lh*396 + (wp + kh)*66 + l32 + kw) << 4));
      s16x8 B1 = *(const s16x8*)(ibc + ((lh*396 + (wp + kh)*66 + 32 + l32 + kw) << 4));
      __builtin_amdgcn_s_setprio(1);
      acc0 = __builtin_amdgcn_mfma_f32_32x32x16_bf16(A, B0, acc0, 0, 0, 0);
      acc1 = __builtin_amdgcn_mfma_f32_32x32x16_bf16(A, B1, acc1, 0, 0, 0);
      __builtin_amdgcn_s_setprio(0);
      pp ^= 1;
    }
  }

  // ---- epilogue: y NCHW f32 (+bias) + fused BN stats ----
  int h = h0 + wp;
#pragma unroll
  for (int rr = 0; rr < 16; ++rr){
    int o = obase + wo*32 + (rr & 3) + 8*(rr >> 2) + 4*lh;
    float bo = bias[o];
    float v0 = acc0[rr] + bo;
    float v1 = acc1[rr] + bo;
    float* yp = y + ((size_t)(b*256 + o)*64 + h)*64;
    yp[l32]      = v0;
    yp[32 + l32] = v1;
    float s = v0 + v1, q = v0*v0 + v1*v1;
#pragma unroll
    for (int m = 1; m < 32; m <<= 1){
      s += __shfl_xor(s, m, 64);
      q += __shfl_xor(q, m, 64);
    }
    if (l32 == 0){
      atomicAdd(&statsY[o*2],     s);
      atomicAdd(&statsY[o*2 + 1], q);
    }
  }
}

__global__ void k_fin_Y(const float* __restrict__ statsY, const float* __restrict__ g,
                        const float* __restrict__ be, float* __restrict__ bnY){
  int o = blockIdx.x*blockDim.x + threadIdx.x;
  if (o >= 256) return;
  const float n = 65536.f;
  float mean = statsY[o*2] / n;
  float var  = statsY[o*2+1] / n - mean*mean;
  float sc = g[o] * rsqrtf(var + 1e-5f);
  bnY[o*2]   = sc;
  bnY[o*2+1] = be[o] - mean*sc;
}

__global__ __launch_bounds__(256) void k_bn_out(float* __restrict__ y,
                                                const float* __restrict__ bnY){
  int gI = blockIdx.x*256 + threadIdx.x;   // 4194304 float4's
  int o = (gI >> 10) & 255;
  float sc = bnY[o*2], sh = bnY[o*2+1];
  f32x4 v = ((const f32x4*)y)[gI];
  v.x = fmaxf(v.x*sc + sh, 0.f);
  v.y = fmaxf(v.y*sc + sh, 0.f);
  v.z = fmaxf(v.z*sc + sh, 0.f);
  v.w = fmaxf(v.w*sc + sh, 0.f);
  ((f32x4*)y)[gI] = v;
}

extern "C" void kernel_launch(void* const* d_in, const int* in_sizes, int n_in,
                              void* d_out, int out_size, void* d_ws, size_t ws_size,
                              hipStream_t stream) {
  const float* x       = (const float*)d_in[0];
  const float* conv_w  = (const float*)d_in[1];
  const float* bn_g    = (const float*)d_in[2];
  const float* bn_b    = (const float*)d_in[3];
  const float* convW_w = (const float*)d_in[4];
  const float* convW_b = (const float*)d_in[5];
  const float* bnW_g   = (const float*)d_in[6];
  const float* bnW_b   = (const float*)d_in[7];
  float* out = (float*)d_out;

  unsigned char* base = (unsigned char*)d_ws;
  unsigned short* Cb   = (unsigned short*)base;                          // 64 MiB NHWC bf16 [16][64][64][512]
  unsigned short* cw_b = (unsigned short*)(base + (64u<<20));            // 128 KiB
  unsigned short* Wb   = (unsigned short*)(base + (64u<<20) + (1u<<20)); // 2.25 MiB
  unsigned short* guard= (unsigned short*)(base + (67u<<20) + (512u<<10)); // 256 B zeros
  float* statsA        = (float*)(base + (68u<<20));                     // 2048 f
  float* statsY        = statsA + 2048;                                  // 512 f
  float* bnA           = statsA + 2560;                                  // 2048 f
  float* bnY           = bnA + 2048;                                     // 512 f

  float* sub = out;   // subbands scratch lives in d_out (exactly 64 MiB), overwritten later by conv output

  hipLaunchKernelGGL(k_cvt_cw, dim3(256), dim3(256), 0, stream, conv_w, cw_b);
  hipLaunchKernelGGL(k_cvt_wb, dim3(1152), dim3(256), 0, stream, convW_w, Wb);
  hipLaunchKernelGGL(k_x_nhwc, dim3(1024), dim3(256), 0, stream, x, Cb);
  hipMemsetAsync(statsA, 0, 2560*sizeof(float), stream);
  hipMemsetAsync(guard, 0, 256, stream);
  hipLaunchKernelGGL(k_gemm1_dwt, dim3(2048), dim3(256), 0, stream, Cb, cw_b, sub);
  hipLaunchKernelGGL(k_stats_sub, dim3(512), dim3(256), 0, stream, sub, statsA);
  hipLaunchKernelGGL(k_fin_A, dim3(4), dim3(256), 0, stream, statsA, bn_g, bn_b, bnA);
  hipLaunchKernelGGL(k_bn_idwt, dim3(512), dim3(256), 0, stream, sub, bnA, Cb);
  hipLaunchKernelGGL(k_conv3, dim3(1024), dim3(512), 0, stream, Cb, Wb, guard, convW_b, out, statsY);
  hipLaunchKernelGGL(k_fin_Y, dim3(1), dim3(256), 0, stream, statsY, bnW_g, bnW_b, bnY);
  hipLaunchKernelGGL(k_bn_out, dim3(16384), dim3(256), 0, stream, out, bnY);
}

// Round 7
// 414.659 us; speedup vs baseline: 1.5483x; 1.5483x over previous
//
#include <hip/hip_runtime.h>
#include <hip/hip_bf16.h>

#define SQ2 0.70710678118654752440f

typedef __attribute__((ext_vector_type(4))) float f32x4;
typedef __attribute__((ext_vector_type(16))) float f32x16;
typedef __attribute__((ext_vector_type(8))) short s16x8;
typedef __attribute__((ext_vector_type(8))) unsigned short u16x8;

// B=16, Cin=256, H=W=64.  rimg channels = 512 (0..255 = branch0, 256..511 = x identity)

__device__ __forceinline__ unsigned short f2bf(float f){
  unsigned u = __builtin_bit_cast(unsigned, f);
  u += 0x7FFFu + ((u >> 16) & 1u);
  return (unsigned short)(u >> 16);
}

__device__ __forceinline__ void gload16(const void* g, const void* l){
  __builtin_amdgcn_global_load_lds((const __attribute__((address_space(1))) void*)g,
                                   (__attribute__((address_space(3))) void*)l, 16, 0, 0);
}

// ---------------- weight converts ----------------
__global__ void k_cvt_cw(const float* __restrict__ w, unsigned short* __restrict__ o){
  int g = blockIdx.x * blockDim.x + threadIdx.x;
  if (g < 256*256) o[g] = f2bf(w[g]);
}

// convW_w [o=256][cin=512][kh=3][kw=3] f32  ->  Wb [tap=kh*3+kw][o][cin] bf16
__global__ void k_cvt_wb(const float* __restrict__ w, unsigned short* __restrict__ o){
  const int N = 256*512*9;
  for (int g = blockIdx.x*blockDim.x + threadIdx.x; g < N; g += gridDim.x*blockDim.x){
    int tap = g % 9;
    int t2  = g / 9;
    int cin = t2 & 511;
    int oc  = t2 >> 9;
    o[(tap*256 + oc)*512 + cin] = f2bf(w[g]);
  }
}

// ---------------- x (NCHW f32) -> Cb NHWC bf16, channels 256..511 ----------------
// 16B vectorized stores (was 2B scalar scattered).
__global__ __launch_bounds__(256) void k_x_nhwc(const float* __restrict__ x,
                                                unsigned short* __restrict__ Cb){
  __shared__ float tile[64][65];       // [w][c], pad 65: conflict-free loads
  int bh = blockIdx.x;                 // b*64 + h
  int b = bh >> 6, h = bh & 63;
  int t = threadIdx.x;
  int wl = t & 63, c4 = t >> 6;        // load role: 64w x 4 c-groups(16)
  int cg = t & 7,  wq = t >> 3;        // store role: 8 c-groups(8) x 32 w
  for (int cc = 0; cc < 256; cc += 64){
#pragma unroll
    for (int r = 0; r < 16; ++r){
      int c = c4*16 + r;
      tile[wl][c] = x[((b*256 + cc + c)*64 + h)*64 + wl];
    }
    __syncthreads();
#pragma unroll
    for (int r = 0; r < 2; ++r){
      int w = wq + 32*r;
      u16x8 v;
#pragma unroll
      for (int i = 0; i < 8; ++i) v[i] = f2bf(tile[w][cg*8 + i]);
      *(u16x8*)(Cb + ((b*64 + h)*64 + w)*512 + 256 + cc + cg*8) = v;
    }
    __syncthreads();
  }
}

// ---------------- fused 1x1 conv (bf16 MFMA) + Haar DWT -> subbands f32 ----------------
// subbands layout: [s=0(A),1(H),2(V),3(D)][b=16][i=32][j=32][o=256] f32 (lives in d_out)
__global__ __launch_bounds__(256) void k_gemm1_dwt(const unsigned short* __restrict__ Cb,
                                                   const unsigned short* __restrict__ cw,
                                                   float* __restrict__ sub){
  int d = blockIdx.x;                      // 2048 = 16b * 32rowpair * 4otile (XCD-swizzled)
  int xcd = d & 7, idx = d >> 3;           // idx 0..255
  int b = xcd*2 + (idx >> 7);
  int rest = idx & 127;
  int rp = rest >> 2, ot = rest & 3;
  int tid = threadIdx.x, wave = tid >> 6, l = tid & 63;
  int l16 = l & 15, lg = l >> 4;
  int obase = ot * 64;
  f32x4 acc[2][4];
#pragma unroll
  for (int i = 0; i < 2; ++i)
#pragma unroll
    for (int j = 0; j < 4; ++j) acc[i][j] = (f32x4)0.0f;

  // pixel p = wave*32 + mt*16 + (lane part);  p = 2*w + rr  (rr = row within pair)
  for (int cc = 0; cc < 256; cc += 32){
    s16x8 a[2], bf[4];
#pragma unroll
    for (int mt = 0; mt < 2; ++mt){
      int p  = wave*32 + mt*16 + l16;
      int w  = p >> 1, rr = p & 1;
      int hin = rp*2 + rr;
      a[mt] = *(const s16x8*)(Cb + ((b*64 + hin)*64 + w)*512 + 256 + cc + lg*8);
    }
#pragma unroll
    for (int nt = 0; nt < 4; ++nt){
      int o = obase + nt*16 + l16;
      bf[nt] = *(const s16x8*)(cw + o*256 + cc + lg*8);
    }
#pragma unroll
    for (int mt = 0; mt < 2; ++mt)
#pragma unroll
      for (int nt = 0; nt < 4; ++nt)
        acc[mt][nt] = __builtin_amdgcn_mfma_f32_16x16x32_bf16(a[mt], bf[nt], acc[mt][nt], 0, 0, 0);
  }

#pragma unroll
  for (int mt = 0; mt < 2; ++mt){
    int j = wave*8 + mt*4 + lg;            // column index in subband
#pragma unroll
    for (int nt = 0; nt < 4; ++nt){
      int o = obase + nt*16 + l16;
      f32x4 v = acc[mt][nt];
      float lo0 = (v.x + v.y)*SQ2, hi0 = (v.x - v.y)*SQ2;
      float lo1 = (v.z + v.w)*SQ2, hi1 = (v.z - v.w)*SQ2;
      float cA = (lo0 + lo1)*SQ2, cV = (lo0 - lo1)*SQ2;
      float cH = (hi0 + hi1)*SQ2, cD = (hi0 - hi1)*SQ2;
      int base = ((b*32 + rp)*32 + j)*256 + o;
      sub[base]              = cA;
      sub[base +   4194304]  = cH;
      sub[base + 2*4194304]  = cV;
      sub[base + 3*4194304]  = cD;
    }
  }
}

// ---------------- per-subband per-channel batch stats ----------------
__global__ __launch_bounds__(256) void k_stats_sub(const float* __restrict__ sub,
                                                   float* __restrict__ statsA){
  int bx = blockIdx.x;                 // 512 = 4s * 16b * 8posgroup
  int pg = bx & 7, b = (bx >> 3) & 15, s = bx >> 7;
  int t = threadIdx.x;
  const float* base = sub + (size_t)(s*16 + b)*262144 + pg*128*256;
  float sum = 0.f, sq = 0.f;
  for (int pos = 0; pos < 128; ++pos){
    float v = base[pos*256 + t];
    sum += v; sq += v*v;
  }
  atomicAdd(&statsA[(s*256 + t)*2],     sum);
  atomicAdd(&statsA[(s*256 + t)*2 + 1], sq);
}

__global__ void k_fin_A(const float* __restrict__ statsA, const float* __restrict__ gamma,
                        const float* __restrict__ beta, float* __restrict__ bnA){
  int t = blockIdx.x*blockDim.x + threadIdx.x;   // 1024 = 4s*256c
  if (t >= 1024) return;
  int c = t & 255;
  const float n = 16384.f;
  float mean = statsA[t*2] / n;
  float var  = statsA[t*2+1] / n - mean*mean;
  float sc = gamma[c] * rsqrtf(var + 1e-5f);
  bnA[t*2]   = sc;
  bnA[t*2+1] = beta[c] - mean*sc;
}

// ---------------- BN + ReLU + IDWT -> Cb NHWC bf16 channels 0..255 ----------------
// 8 channels per thread: f32x4 loads, 16B stores (was 2B scalar).
__global__ __launch_bounds__(256) void k_bn_idwt(const float* __restrict__ sub,
                                                 const float* __restrict__ bnA,
                                                 unsigned short* __restrict__ Cb){
  int bx = blockIdx.x;                 // 512 = 16b * 32i
  int b = bx >> 5, i = bx & 31;
  int t = threadIdx.x;
  int cg = t & 31, jp = t >> 5;        // c0 = cg*8 ; j = jp*4 + jj
  int c0 = cg*8;
  float sc[4][8], sh[4][8];
#pragma unroll
  for (int s = 0; s < 4; ++s)
#pragma unroll
    for (int k = 0; k < 8; ++k){
      sc[s][k] = bnA[(s*256 + c0 + k)*2];
      sh[s][k] = bnA[(s*256 + c0 + k)*2 + 1];
    }
  for (int jj = 0; jj < 4; ++jj){
    int j = jp*4 + jj;
    size_t idx = ((size_t)((b*32 + i)*32) + j)*256 + c0;
    f32x4 A0 = *(const f32x4*)(sub + idx);
    f32x4 A1 = *(const f32x4*)(sub + idx + 4);
    f32x4 H0 = *(const f32x4*)(sub + idx + 4194304);
    f32x4 H1 = *(const f32x4*)(sub + idx + 4194304 + 4);
    f32x4 V0 = *(const f32x4*)(sub + idx + 2*4194304);
    f32x4 V1 = *(const f32x4*)(sub + idx + 2*4194304 + 4);
    f32x4 D0 = *(const f32x4*)(sub + idx + 3*4194304);
    f32x4 D1 = *(const f32x4*)(sub + idx + 3*4194304 + 4);
    u16x8 o00, o01, o10, o11;
#pragma unroll
    for (int k = 0; k < 8; ++k){
      float av = (k < 4) ? A0[k] : A1[k-4];
      float hv = (k < 4) ? H0[k] : H1[k-4];
      float vv = (k < 4) ? V0[k] : V1[k-4];
      float dv = (k < 4) ? D0[k] : D1[k-4];
      float a  = fmaxf(av * sc[0][k] + sh[0][k], 0.f);
      float hh = fmaxf(hv * sc[1][k] + sh[1][k], 0.f);
      float v  = fmaxf(vv * sc[2][k] + sh[2][k], 0.f);
      float dd = fmaxf(dv * sc[3][k] + sh[3][k], 0.f);
      float lo_e = (a + v)*SQ2, lo_o = (a - v)*SQ2;
      float hi_e = (hh + dd)*SQ2, hi_o = (hh - dd)*SQ2;
      o00[k] = f2bf((lo_e + hi_e)*SQ2);
      o01[k] = f2bf((lo_o + hi_o)*SQ2);
      o10[k] = f2bf((lo_e - hi_e)*SQ2);
      o11[k] = f2bf((lo_o - hi_o)*SQ2);
    }
    int h2 = 2*i, w2 = 2*j;
    *(u16x8*)(Cb + ((b*64 + h2  )*64 + w2  )*512 + c0) = o00;
    *(u16x8*)(Cb + ((b*64 + h2  )*64 + w2+1)*512 + c0) = o01;
    *(u16x8*)(Cb + ((b*64 + h2+1)*64 + w2  )*512 + c0) = o10;
    *(u16x8*)(Cb + ((b*64 + h2+1)*64 + w2+1)*512 + c0) = o11;
  }
}

// ---------------- 3x3 conv, 512->256, implicit GEMM, 32x32x16 MFMA, counted-vmcnt pipeline ----
// (R5-measured version: 177.9 us, MfmaUtil 38%, conflicts 0 — reverted verbatim)
// Block: 256 o x (8 rows x 32 cols), 256 blocks, 512 threads (8 waves: 4 wo x 2 wp).
// Wave: 64 o x 128 px (mt=2, nt=4). K phases: 32 sub-chunks (16ch) x 9 taps = 288.
// LDS: ibuf dbuf 2x16KB  [2 planes(8ch) x 10 rows x 34 cols x 16B, padded to 1024 slots]
//      wbuf dbuf 2x8KB   [2 planes(8ch) x 256 o x 16B]
//      bias 1KB                     total 50176 B
__global__ __launch_bounds__(512, 2) void k_conv3(const unsigned short* __restrict__ Cb,
                                                  const unsigned short* __restrict__ Wb,
                                                  const unsigned short* __restrict__ guard,
                                                  const float* __restrict__ bias,
                                                  float* __restrict__ y){
  __shared__ char sm[50176];

  int d = blockIdx.x;                  // 256 blocks, XCD-swizzled: 2 images per XCD
  int xcd = d & 7, idx = d >> 3;       // idx 0..31
  int b  = xcd*2 + (idx >> 4);
  int r  = idx & 15;
  int rg = r >> 1;                     // 0..7 : 8-row group
  int cg = r & 1;                      // 0..1 : 32-col group
  int h0 = rg*8, c0 = cg*32;

  int tid = threadIdx.x, wv = tid >> 6, l = tid & 63;
  int l32 = l & 31, lh = l >> 5;
  int wo = wv >> 1, wp = wv & 1;

  if (tid < 256) *(float*)(sm + 49152 + tid*4) = bias[tid];

  // ---- input staging: 2 gload16 per wave per sub-chunk ----
  const unsigned short* ip[2];
  int iadv[2], ilds[2];
#pragma unroll
  for (int k = 0; k < 2; ++k){
    int j = (wv + 8*k)*64 + l;         // 0..1023
    ilds[k] = j*16;
    const unsigned short* p = guard; int adv = 0;
    if (j < 680){
      int lgp = j / 340, pp = j % 340;
      int rr = pp / 34, c = pp % 34;
      int hin = h0 - 1 + rr, win = c0 - 1 + c;
      if ((unsigned)hin < 64u && (unsigned)win < 64u){
        p = Cb + (((b*64 + hin)*64 + win)*512 + lgp*8);
        adv = 16;
      }
    }
    ip[k] = p; iadv[k] = adv;
  }

  // ---- weight staging: 1 gload16 per wave per phase ----
  int jw = wv*64 + l;                  // 0..511
  const unsigned short* wg = Wb + (jw & 255)*512 + (jw >> 8)*8;   // + tap*131072 + sc*16
  int wlds = jw*16;

  f32x16 acc[2][4];
#pragma unroll
  for (int mt = 0; mt < 2; ++mt)
#pragma unroll
    for (int nt = 0; nt < 4; ++nt) acc[mt][nt] = (f32x16)0.0f;

  // ---- prologue: stage I(0) into ibuf0, W(0,0) into wbuf0 ----
  gload16(ip[0], sm + ilds[0]);
  gload16(ip[1], sm + ilds[1]);
  gload16(wg,    sm + 32768 + wlds);
  __syncthreads();                     // full drain once (also publishes bias)

  int scpar = 0;
  for (int sc = 0; sc < 32; ++sc){
    char* ibc = sm + scpar*16384;
    char* ibn = sm + (scpar^1)*16384;
#pragma unroll
    for (int tau = 0; tau < 9; ++tau){
      int wpar = (scpar + tau) & 1;
      char* wbc = sm + 32768 + wpar*8192;
      char* wbn = sm + 32768 + (wpar^1)*8192;

      __builtin_amdgcn_s_barrier();                    // closes previous phase's reads
      if (tau < 8) gload16(wg + (tau+1)*131072, wbn + wlds);   // W(sc, tau+1)
      else         gload16(wg + 16,             wbn + wlds);   // W(sc+1, 0)
      if (tau == 7){                                   // next-chunk input, 2 phases early
        ip[0] += iadv[0]; ip[1] += iadv[1];
        gload16(ip[0], ibn + ilds[0]);
        gload16(ip[1], ibn + ilds[1]);
      }
      if (tau == 8) asm volatile("s_waitcnt vmcnt(3)" ::: "memory");
      else          asm volatile("s_waitcnt vmcnt(1)" ::: "memory");
      __builtin_amdgcn_s_barrier();                    // staged data visible to all waves

      const int kh = tau / 3, kw = tau % 3;
      s16x8 A[2], Bf[4];
#pragma unroll
      for (int mt = 0; mt < 2; ++mt)
        A[mt] = *(const s16x8*)(wbc + (lh*256 + wo*64 + mt*32 + l32)*16);
#pragma unroll
      for (int nt = 0; nt < 4; ++nt)
        Bf[nt] = *(const s16x8*)(ibc + (lh*340 + (wp*4 + nt + kh)*34 + l32 + kw)*16);
      __builtin_amdgcn_s_setprio(1);
#pragma unroll
      for (int mt = 0; mt < 2; ++mt)
#pragma unroll
        for (int nt = 0; nt < 4; ++nt)
          acc[mt][nt] = __builtin_amdgcn_mfma_f32_32x32x16_bf16(A[mt], Bf[nt], acc[mt][nt], 0, 0, 0);
      __builtin_amdgcn_s_setprio(0);
    }
    wg += 16;
    scpar ^= 1;
  }

  // ---- epilogue: y NCHW f32 (+bias).  C layout: col=l&31, row=(reg&3)+8*(reg>>2)+4*(l>>5) ----
#pragma unroll
  for (int mt = 0; mt < 2; ++mt){
#pragma unroll
    for (int nt = 0; nt < 4; ++nt){
      int pr = wp*4 + nt, pc = l32;
      f32x16 v = acc[mt][nt];
#pragma unroll
      for (int rr = 0; rr < 16; ++rr){
        int row = (rr & 3) + 8*(rr >> 2) + 4*lh;
        int o = wo*64 + mt*32 + row;
        float bo = *(const float*)(sm + 49152 + o*4);
        y[((b*256 + o)*64 + (h0 + pr))*64 + c0 + pc] = v[rr] + bo;
      }
    }
  }
}

// ---------------- final BN stats + apply ----------------
__global__ __launch_bounds__(256) void k_stats_y(const float* __restrict__ y,
                                                 const float* __restrict__ g,
                                                 const float* __restrict__ be,
                                                 float* __restrict__ bnY){
  int o = blockIdx.x;                  // 256
  int t = threadIdx.x;
  float sum = 0.f, sq = 0.f;
  for (int idx = t; idx < 16384; idx += 256){
    int bb = idx >> 10, p4 = idx & 1023;
    f32x4 v = *(const f32x4*)(y + (size_t)(bb*256 + o)*4096 + p4*4);
    sum += v.x + v.y + v.z + v.w;
    sq  += v.x*v.x + v.y*v.y + v.z*v.z + v.w*v.w;
  }
  __shared__ float s1[256], s2[256];
  s1[t] = sum; s2[t] = sq;
  __syncthreads();
  for (int off = 128; off; off >>= 1){
    if (t < off){ s1[t] += s1[t+off]; s2[t] += s2[t+off]; }
    __syncthreads();
  }
  if (t == 0){
    const float n = 65536.f;
    float mean = s1[0] / n;
    float var  = s2[0] / n - mean*mean;
    float sc = g[o] * rsqrtf(var + 1e-5f);
    bnY[o*2]   = sc;
    bnY[o*2+1] = be[o] - mean*sc;
  }
}

__global__ __launch_bounds__(256) void k_bn_out(float* __restrict__ y,
                                                const float* __restrict__ bnY){
  int gI = blockIdx.x*256 + threadIdx.x;   // 4194304 float4's
  int o = (gI >> 10) & 255;
  float sc = bnY[o*2], sh = bnY[o*2+1];
  f32x4 v = ((const f32x4*)y)[gI];
  v.x = fmaxf(v.x*sc + sh, 0.f);
  v.y = fmaxf(v.y*sc + sh, 0.f);
  v.z = fmaxf(v.z*sc + sh, 0.f);
  v.w = fmaxf(v.w*sc + sh, 0.f);
  ((f32x4*)y)[gI] = v;
}

extern "C" void kernel_launch(void* const* d_in, const int* in_sizes, int n_in,
                              void* d_out, int out_size, void* d_ws, size_t ws_size,
                              hipStream_t stream) {
  const float* x       = (const float*)d_in[0];
  const float* conv_w  = (const float*)d_in[1];
  const float* bn_g    = (const float*)d_in[2];
  const float* bn_b    = (const float*)d_in[3];
  const float* convW_w = (const float*)d_in[4];
  const float* convW_b = (const float*)d_in[5];
  const float* bnW_g   = (const float*)d_in[6];
  const float* bnW_b   = (const float*)d_in[7];
  float* out = (float*)d_out;

  unsigned char* base = (unsigned char*)d_ws;
  unsigned short* Cb   = (unsigned short*)base;                          // 64 MiB NHWC bf16 [16][64][64][512]
  unsigned short* cw_b = (unsigned short*)(base + (64u<<20));            // 128 KiB
  unsigned short* Wb   = (unsigned short*)(base + (64u<<20) + (1u<<20)); // 2.25 MiB
  unsigned short* guard= (unsigned short*)(base + (67u<<20) + (512u<<10)); // 256 B zeros
  float* statsA        = (float*)(base + (68u<<20));                     // 2048 f
  float* bnA           = statsA + 2048;
  float* bnY           = bnA + 2048;

  float* sub = out;   // subbands scratch lives in d_out (exactly 64 MiB), overwritten later by conv output

  hipLaunchKernelGGL(k_cvt_cw, dim3(256), dim3(256), 0, stream, conv_w, cw_b);
  hipLaunchKernelGGL(k_cvt_wb, dim3(1152), dim3(256), 0, stream, convW_w, Wb);
  hipLaunchKernelGGL(k_x_nhwc, dim3(1024), dim3(256), 0, stream, x, Cb);
  hipMemsetAsync(statsA, 0, 4*256*2*sizeof(float), stream);
  hipMemsetAsync(guard, 0, 256, stream);
  hipLaunchKernelGGL(k_gemm1_dwt, dim3(2048), dim3(256), 0, stream, Cb, cw_b, sub);
  hipLaunchKernelGGL(k_stats_sub, dim3(512), dim3(256), 0, stream, sub, statsA);
  hipLaunchKernelGGL(k_fin_A, dim3(4), dim3(256), 0, stream, statsA, bn_g, bn_b, bnA);
  hipLaunchKernelGGL(k_bn_idwt, dim3(512), dim3(256), 0, stream, sub, bnA, Cb);
  hipLaunchKernelGGL(k_conv3, dim3(256), dim3(512), 0, stream, Cb, Wb, guard, convW_b, out);
  hipLaunchKernelGGL(k_stats_y, dim3(256), dim3(256), 0, stream, out, bnW_g, bnW_b, bnY);
  hipLaunchKernelGGL(k_bn_out, dim3(16384), dim3(256), 0, stream, out, bnY);
}